// Round 8
// baseline (200.851 us; speedup 1.0000x reference)
//
#include <hip/hip_runtime.h>

// ROI Align (FPN, PH=PW=7, SR=2), fp32 I/O.
// R8 = R7 (paired-x dwordx2 gathers, transaction model confirmed) +
//  (1) CPT=2: two adjacent channels per thread -> same total gather
//      instructions, half the per-output geometry/decomposition cost;
//  (2) factored y/x geometry (2+2 instead of 4 full samples);
//  (3) XCD-aware swizzle: each XCD gets a contiguous band of 64 ROIs
//      (L2 locality; heuristic only, correctness-neutral).
// Model: T ~= 39us * (M wave-gathers) + fixed; this round halves `fixed`.

#define NUM_CH 256

typedef float floatx2 __attribute__((ext_vector_type(2)));

__global__ __launch_bounds__(256) void roi_align_kernel(
    const float* __restrict__ f0,
    const float* __restrict__ f1,
    const float* __restrict__ f2,
    const float* __restrict__ f3,
    const float* __restrict__ rois_f,
    const int* __restrict__ level,
    float* __restrict__ out,
    int total)
{
    // XCD clustering: dispatch sends block b to XCD b%8 (round-robin
    // heuristic). Remap so XCD x runs contiguous work-blocks -> contiguous
    // ROI band. Identity when grid isn't divisible by 8.
    int b = blockIdx.x;
    int nb = gridDim.x;
    int wb = b;
    if ((nb & 7) == 0) {
        int per = nb >> 3;
        wb = (b & 7) * per + (b >> 3);
    }

    int e = wb * 256 + threadIdx.x;
    if (e >= total) return;

    int p  = e % 49;            // output pixel
    int t  = e / 49;
    int cp = t % (NUM_CH / 2);  // channel pair
    int k  = t / (NUM_CH / 2);  // roi
    int ph = p / 7;
    int pw = p % 7;
    int c0 = cp * 2;

    int lvl = level[k];
    const float* f;
    int H, W; float scale;
    if (lvl == 0)      { f = f0; H = 200; W = 200; scale = 0.25f;    }
    else if (lvl == 1) { f = f1; H = 100; W = 100; scale = 0.125f;   }
    else if (lvl == 2) { f = f2; H = 50;  W = 50;  scale = 0.0625f;  }
    else               { f = f3; H = 25;  W = 25;  scale = 0.03125f; }

    const float* rf = rois_f + (size_t)k * 5;
    float r0 = rf[0];
    float x1 = rf[1] * scale, y1 = rf[2] * scale;
    float x2 = rf[3] * scale, y2 = rf[4] * scale;
    int bi = (int)r0;
    bi = (bi < 0) ? 0 : ((bi > 1) ? 1 : bi);

    float bh = fmaxf(y2 - y1, 1.0f) * (1.0f / 7.0f);
    float bw = fmaxf(x2 - x1, 1.0f) * (1.0f / 7.0f);

    const size_t HW = (size_t)(H * W);
    const float* base0 = f + ((size_t)bi * NUM_CH + c0) * HW;

    // ---- factored geometry: 2 y-samples + 2 x-samples ---------------------
    int   rA[2], rB[2];            // row offsets (yl*W, yh*W)
    float lyv[2], hyv[2], vy[2];
    #pragma unroll
    for (int sy = 0; sy < 2; ++sy) {
        float y = y1 + (float)ph * bh + ((float)sy + 0.5f) * (bh * 0.5f);
        bool valid = (y > -1.0f) && (y < (float)H);
        float yc = fmaxf(y, 0.0f);
        int yl = min((int)yc, H - 1);
        int yh = min(yl + 1, H - 1);
        float ly = (yl >= H - 1) ? 0.0f : (yc - (float)yl);
        rA[sy] = yl * W;
        rB[sy] = yh * W;
        lyv[sy] = ly; hyv[sy] = 1.0f - ly;
        vy[sy] = valid ? 0.25f : 0.0f;     // fold 2x2 mean into y validity
    }
    int   xb[2];
    float lxv[2], hxv[2], sel[2], vx[2];
    #pragma unroll
    for (int sx = 0; sx < 2; ++sx) {
        float x = x1 + (float)pw * bw + ((float)sx + 0.5f) * (bw * 0.5f);
        bool valid = (x > -1.0f) && (x < (float)W);
        float xc = fmaxf(x, 0.0f);
        int xl = min((int)xc, W - 1);
        float lx = (xl >= W - 1) ? 0.0f : (xc - (float)xl);
        int xq = min(xl, W - 2);           // pair base; lx==0 when clamped
        xb[sx] = xq;
        sel[sx] = (xl > xq) ? 1.0f : 0.0f;
        lxv[sx] = lx; hxv[sx] = 1.0f - lx;
        vx[sx] = valid ? 1.0f : 0.0f;
    }

    // ---- 16 independent dwordx2 gathers (4 samples x 2 rows x 2 channels) -
    floatx2 va0[4], vb0[4], va1[4], vb1[4];
    #pragma unroll
    for (int s = 0; s < 4; ++s) {
        int sy = s >> 1, sx = s & 1;
        int oA = rA[sy] + xb[sx];
        int oB = rB[sy] + xb[sx];
        va0[s] = *(const floatx2*)(base0 + oA);
        vb0[s] = *(const floatx2*)(base0 + oB);
        va1[s] = *(const floatx2*)(base0 + HW + oA);
        vb1[s] = *(const floatx2*)(base0 + HW + oB);
    }

    float acc0 = 0.0f, acc1 = 0.0f;
    #pragma unroll
    for (int s = 0; s < 4; ++s) {
        int sy = s >> 1, sx = s & 1;
        float vs  = vy[sy] * vx[sx];
        float w00 = hyv[sy] * hxv[sx] * vs;
        float w01 = hyv[sy] * lxv[sx] * vs;
        float w10 = lyv[sy] * hxv[sx] * vs;
        float w11 = lyv[sy] * lxv[sx] * vs;
        float s0  = sel[sx];

        float a00 = va0[s].x + s0 * (va0[s].y - va0[s].x);
        float a10 = vb0[s].x + s0 * (vb0[s].y - vb0[s].x);
        acc0 += w00 * a00 + w01 * va0[s].y + w10 * a10 + w11 * vb0[s].y;

        float b00 = va1[s].x + s0 * (va1[s].y - va1[s].x);
        float b10 = vb1[s].x + s0 * (vb1[s].y - vb1[s].x);
        acc1 += w00 * b00 + w01 * va1[s].y + w10 * b10 + w11 * vb1[s].y;
    }

    size_t ob = ((size_t)k * NUM_CH + c0) * 49 + p;
    out[ob]      = acc0;
    out[ob + 49] = acc1;
}

extern "C" void kernel_launch(void* const* d_in, const int* in_sizes, int n_in,
                              void* d_out, int out_size, void* d_ws, size_t ws_size,
                              hipStream_t stream) {
    const float* f0   = (const float*)d_in[0];
    const float* f1   = (const float*)d_in[1];
    const float* f2   = (const float*)d_in[2];
    const float* f3   = (const float*)d_in[3];
    const float* rois = (const float*)d_in[4];
    // d_in[5] = rois_counts (unused)
    const int* level = (const int*)d_in[6];
    float* out = (float*)d_out;

    int total = out_size / 2;   // K * 128 * 49 threads, 2 channels each
    int threads = 256;
    int blocks = (total + threads - 1) / threads;
    roi_align_kernel<<<blocks, threads, 0, stream>>>(f0, f1, f2, f3, rois, level, out, total);
}

// Round 9
// 186.430 us; speedup vs baseline: 1.0774x; 1.0774x over previous
//
#include <hip/hip_runtime.h>

// ROI Align (FPN, PH=PW=7, SR=2), fp32 I/O.
// R9 = R7 (best: 73.5us) + per-ROI-uniform x4-merged gathers.
// Model (R4/R5/R7/R8 consistent): critical path is the vector-memory
// transaction pipe; VALU overlaps freely (R8: VALUBusy halved, time rose).
// When bin_w <= 3.98 the two x-subsamples' corners fit in one 4-float
// window -> one dwordx4 per (sample-row) replaces two dwordx2: 8 -> 4
// gathers/thread. bin_w is per-ROI uniform; waves never straddle ROIs
// (196 waves/ROI) -> branch is wave-uniform. Extraction = cndmask (free).
// XCD swizzle and CPT=2 from R8 reverted (caused the regression).

#define NUM_CH 256

typedef float floatx2 __attribute__((ext_vector_type(2)));
typedef float floatx4 __attribute__((ext_vector_type(4)));

__device__ __forceinline__ float ext4(floatx4 v, int i) {
    float r = (i == 1) ? v.y : v.x;
    r = (i == 2) ? v.z : r;
    r = (i == 3) ? v.w : r;
    return r;
}

__global__ __launch_bounds__(256) void roi_align_kernel(
    const float* __restrict__ f0,
    const float* __restrict__ f1,
    const float* __restrict__ f2,
    const float* __restrict__ f3,
    const float* __restrict__ rois_f,
    const int* __restrict__ level,
    float* __restrict__ out,
    int total)
{
    int e = blockIdx.x * blockDim.x + threadIdx.x;
    if (e >= total) return;

    int p  = e % 49;           // output pixel (lane-minor, coalesced store)
    int t  = e / 49;
    int c  = t % NUM_CH;       // channel
    int k  = t / NUM_CH;       // roi
    int ph = p / 7;
    int pw = p % 7;

    int lvl = level[k];
    const float* f;
    int H, W; float scale;
    if (lvl == 0)      { f = f0; H = 200; W = 200; scale = 0.25f;    }
    else if (lvl == 1) { f = f1; H = 100; W = 100; scale = 0.125f;   }
    else if (lvl == 2) { f = f2; H = 50;  W = 50;  scale = 0.0625f;  }
    else               { f = f3; H = 25;  W = 25;  scale = 0.03125f; }

    const float* rf = rois_f + (size_t)k * 5;
    float r0 = rf[0];
    float x1 = rf[1] * scale, y1 = rf[2] * scale;
    float x2 = rf[3] * scale, y2 = rf[4] * scale;
    int bi = (int)r0;
    bi = (bi < 0) ? 0 : ((bi > 1) ? 1 : bi);

    float bh = fmaxf(y2 - y1, 1.0f) * (1.0f / 7.0f);
    float bw = fmaxf(x2 - x1, 1.0f) * (1.0f / 7.0f);

    const float* base = f + ((size_t)bi * NUM_CH + c) * (size_t)(H * W);

    // ---- factored geometry: 2 y-samples + 2 x-samples ---------------------
    int   rA[2], rB[2];
    float lyv[2], hyv[2], vy[2];
    #pragma unroll
    for (int sy = 0; sy < 2; ++sy) {
        float y = y1 + (float)ph * bh + ((float)sy + 0.5f) * (bh * 0.5f);
        bool valid = (y > -1.0f) && (y < (float)H);
        float yc = fmaxf(y, 0.0f);
        int yl = min((int)yc, H - 1);
        int yh = min(yl + 1, H - 1);
        float ly = (yl >= H - 1) ? 0.0f : (yc - (float)yl);
        rA[sy] = yl * W;
        rB[sy] = yh * W;
        lyv[sy] = ly; hyv[sy] = 1.0f - ly;
        vy[sy] = valid ? 0.25f : 0.0f;     // fold 2x2 mean into y validity
    }
    int   xlv[2], xhv[2];
    float lxv[2], hxv[2], vx[2];
    #pragma unroll
    for (int sx = 0; sx < 2; ++sx) {
        float x = x1 + (float)pw * bw + ((float)sx + 0.5f) * (bw * 0.5f);
        bool valid = (x > -1.0f) && (x < (float)W);
        float xc = fmaxf(x, 0.0f);
        int xl = min((int)xc, W - 1);
        float lx = (xl >= W - 1) ? 0.0f : (xc - (float)xl);
        xlv[sx] = xl;
        xhv[sx] = min(xl + 1, W - 1);
        lxv[sx] = lx; hxv[sx] = 1.0f - lx;
        vx[sx] = valid ? 1.0f : 0.0f;
    }

    float acc = 0.0f;

    if (bw <= 3.98f) {
        // ---- merged path: x-span of all 4 x-corners fits a 4-float window -
        int xq = min(xlv[0], W - 4);               // window base (>=0: W>=25)
        int i0l = min(max(xlv[0] - xq, 0), 3);
        int i0h = min(max(xhv[0] - xq, 0), 3);
        int i1l = min(max(xlv[1] - xq, 0), 3);
        int i1h = min(max(xhv[1] - xq, 0), 3);

        floatx4 LA0 = *(const floatx4*)(base + rA[0] + xq);  // sy0 row yl
        floatx4 LB0 = *(const floatx4*)(base + rB[0] + xq);  // sy0 row yh
        floatx4 LA1 = *(const floatx4*)(base + rA[1] + xq);  // sy1 row yl
        floatx4 LB1 = *(const floatx4*)(base + rB[1] + xq);  // sy1 row yh

        #pragma unroll
        for (int sy = 0; sy < 2; ++sy) {
            floatx4 LA = sy ? LA1 : LA0;
            floatx4 LB = sy ? LB1 : LB0;
            #pragma unroll
            for (int sx = 0; sx < 2; ++sx) {
                int il = sx ? i1l : i0l;
                int ih = sx ? i1h : i0h;
                float vs  = vy[sy] * vx[sx];
                float w00 = hyv[sy] * hxv[sx] * vs;
                float w01 = hyv[sy] * lxv[sx] * vs;
                float w10 = lyv[sy] * hxv[sx] * vs;
                float w11 = lyv[sy] * lxv[sx] * vs;
                acc += w00 * ext4(LA, il) + w01 * ext4(LA, ih)
                     + w10 * ext4(LB, il) + w11 * ext4(LB, ih);
            }
        }
    } else {
        // ---- wide-ROI path: R7's 8 dwordx2 gathers ------------------------
        int   xb[2];
        float sel[2];
        #pragma unroll
        for (int sx = 0; sx < 2; ++sx) {
            int xq = min(xlv[sx], W - 2);
            xb[sx]  = xq;
            sel[sx] = (xlv[sx] > xq) ? 1.0f : 0.0f;
        }
        floatx2 va[4], vb[4];
        #pragma unroll
        for (int s = 0; s < 4; ++s) {
            int sy = s >> 1, sx = s & 1;
            va[s] = *(const floatx2*)(base + rA[sy] + xb[sx]);
            vb[s] = *(const floatx2*)(base + rB[sy] + xb[sx]);
        }
        #pragma unroll
        for (int s = 0; s < 4; ++s) {
            int sy = s >> 1, sx = s & 1;
            float vs  = vy[sy] * vx[sx];
            float w00 = hyv[sy] * hxv[sx] * vs;
            float w01 = hyv[sy] * lxv[sx] * vs;
            float w10 = lyv[sy] * hxv[sx] * vs;
            float w11 = lyv[sy] * lxv[sx] * vs;
            float s0  = sel[sx];
            float v00 = va[s].x + s0 * (va[s].y - va[s].x);
            float v10 = vb[s].x + s0 * (vb[s].y - vb[s].x);
            acc += w00 * v00 + w01 * va[s].y + w10 * v10 + w11 * vb[s].y;
        }
    }

    out[e] = acc;
}

extern "C" void kernel_launch(void* const* d_in, const int* in_sizes, int n_in,
                              void* d_out, int out_size, void* d_ws, size_t ws_size,
                              hipStream_t stream) {
    const float* f0   = (const float*)d_in[0];
    const float* f1   = (const float*)d_in[1];
    const float* f2   = (const float*)d_in[2];
    const float* f3   = (const float*)d_in[3];
    const float* rois = (const float*)d_in[4];
    // d_in[5] = rois_counts (unused)
    const int* level = (const int*)d_in[6];
    float* out = (float*)d_out;

    int total = out_size;  // K * 256 * 49
    int threads = 256;
    int blocks = (total + threads - 1) / threads;
    roi_align_kernel<<<blocks, threads, 0, stream>>>(f0, f1, f2, f3, rois, level, out, total);
}